// Round 9
// baseline (149.299 us; speedup 1.0000x reference)
//
#include <hip/hip_runtime.h>
#include <stdint.h>

// Problem constants
#define B_SZ   1024
#define GF     512
#define GC     63
#define NLEAF  64
#define IN_F   512
#define OUT_F  512

typedef float f32x4 __attribute__((ext_vector_type(4)));
typedef __fp16 h16x2 __attribute__((ext_vector_type(2)));
typedef __fp16 h16x8 __attribute__((ext_vector_type(8)));
typedef _Float16 f16x2 __attribute__((ext_vector_type(2)));

union HF8 { f16x2 h2[4]; h16x8 v; uint4 u; };

__device__ inline f16x2 pkrtz(float a, float b) {
  union { h16x2 r; f16x2 f; } u;
  u.r = __builtin_amdgcn_cvt_pkrtz(a, b);
  return u.f;
}

// ---------------------------------------------------------------------------
// Kernel 1: gatings = sigmoid(x_gating @ gw + gb); leaf_probs tree product.
// (unchanged — proven)
// ---------------------------------------------------------------------------
__global__ __launch_bounds__(512, 2) void k_leafprobs(
    const float* __restrict__ xg, const float* __restrict__ gw,
    const float* __restrict__ gb, float* __restrict__ p_ws)
{
  __shared__ float xsr[GF];
  __shared__ float part[512];
  __shared__ float gates[GC + 1];
  const int b = blockIdx.x;
  const int t = threadIdx.x;

  xsr[t] = xg[(size_t)b * GF + t];
  __syncthreads();

  const int ks = t >> 6, g = t & 63;
  float acc = 0.f;
  if (g < GC) {
    const float* gp = gw + (size_t)(ks * 64) * GC + g;
    const float* xp = &xsr[ks * 64];
#pragma unroll 8
    for (int k = 0; k < 64; ++k) acc += xp[k] * gp[(size_t)k * GC];
  }
  part[t] = acc;
  __syncthreads();

  if (t < GC) {
    float s = gb[t];
#pragma unroll
    for (int r = 0; r < 8; ++r) s += part[r * 64 + t];
    gates[t] = 1.f / (1.f + expf(-s));
  }
  __syncthreads();

  if (t < NLEAF) {
    float v = 1.f;
    int idx = 0, start = 0;
#pragma unroll
    for (int d = 0; d < 6; ++d) {
      int bit = (t >> (5 - d)) & 1;
      float gg = gates[start + idx];
      v *= bit ? (1.f - gg) : gg;
      idx = 2 * idx + bit;
      start += (1 << d);
    }
    p_ws[(size_t)b * NLEAF + t] = v;
  }
}

// ---------------------------------------------------------------------------
// Kernel 2 (FUSED, 8-wave 4Mx2N decomposition):
// R1..R8 invariant: 2 waves/SIMD, each serially dependent on its own
// 8x ds_read_b128 -> lgkm -> MFMA chain => MfmaUtil pinned at ~27%.
// This version: 512 thr, waves = 4(M) x 2(N); wave owns 64 rows x 32 cols.
//  * per-wave B ds_reads per i-step: 8 -> 4 b128 (R1's mi=2 split DOUBLED
//    them — confounded; this halves them)
//  * per-wave VGPR ~115 (acc32+prh32+rb16+af16+misc) -> 4 waves/SIMD with
//    2 co-resident blocks (__launch_bounds__(512,4))
//  * TLP: 4 independent dep-chains per SIMD instead of 2
// Stage: thread = (br=tid>>3, seg=tid&7), 8 floats -> 1 swizzled uint4.
// vmcnt ledger (2 loads/BLOAD, slot=tile&1): steady WA=WB=2; drain 2/0.
// pb folded in (kc==0) as one pseudo-i-step with A=prh (proven R8).
// ---------------------------------------------------------------------------
#define SK 16
#define KI 32   // 512 / SK

template <bool ATOMIC>
__global__ __launch_bounds__(512, 4) void k_fused(
    const float* __restrict__ x_leaf,   // [1024][512]
    const float* __restrict__ p_ws,     // [1024][64]
    const float* __restrict__ pw,       // [512][512][64]  ([o][i][l])
    const float* __restrict__ pb,       // [512][64]
    float* __restrict__ dst)            // parts [SK][1024][512] or out
{
  __shared__ __align__(16) float         xs[KI][256];    // 32 KB (transposed)
  __shared__ __align__(16) unsigned char bs8[2 * 16384]; // 2buf x 2sub x 8KB

  const int tid  = threadIdx.x;
  const int lane = tid & 63;
  const int wid  = tid >> 6;        // 0..7
  const int wmg  = wid >> 1;        // 0..3  (M group: 64 rows)
  const int wn   = wid & 1;         // 0..1  (N group: 32 cols)
  const int quad = lane >> 4;
  const int l15  = lane & 15;
  const int l7   = l15 & 7;

  const int bid = blockIdx.x;       // 512
  const int nt  = bid & 7;
  const int mt  = (bid >> 3) & 3;
  const int kc  = bid >> 5;         // 0..15

  const int row_m0 = mt * 256;
  const int o0     = nt * 64;
  const int i0     = kc * KI;
  const int wm     = wmg * 64;      // wave's first row

  // ---- stage x slab transposed [KI][256]: thread = (row=tid&255, half) ----
  {
    const int r = tid & 255;
    const int h = tid >> 8;         // 0..1
    const float* src = x_leaf + (size_t)(row_m0 + r) * IN_F + i0 + h * 16;
#pragma unroll
    for (int q = 0; q < 4; ++q) {
      float4 v = *(const float4*)(src + q * 4);
      const int c = h * 16 + q * 4;
      xs[c + 0][r] = v.x; xs[c + 1][r] = v.y;
      xs[c + 2][r] = v.z; xs[c + 3][r] = v.w;
    }
  }

  // ---- p fragments, converted ONCE to f16 (reused all K) ----
  HF8 prh[4][2];
#pragma unroll
  for (int mi = 0; mi < 4; ++mi) {
    const int row = row_m0 + wm + mi * 16 + l15;
#pragma unroll
    for (int ks = 0; ks < 2; ++ks) {
      const f32x4* src = (const f32x4*)(p_ws + (size_t)row * NLEAF + ks * 32 + quad * 8);
      f32x4 lo = src[0], hi = src[1];
      prh[mi][ks].h2[0] = pkrtz(lo[0], lo[1]);
      prh[mi][ks].h2[1] = pkrtz(lo[2], lo[3]);
      prh[mi][ks].h2[2] = pkrtz(hi[0], hi[1]);
      prh[mi][ks].h2[3] = pkrtz(hi[2], hi[3]);
    }
  }

  // ---- B-load geometry: thread = (br = tid>>3 of 64 o-rows, seg = tid&7) ----
  const int br  = tid >> 3;
  const int seg = tid & 7;          // 8 floats each
  const float* bsrc0 = pw + ((size_t)(o0 + br) * IN_F + i0) * NLEAF + seg * 8;

  // swizzled LDS offsets (XOR in byte bits 4-6; fields don't carry)
  const int woff = br * 128 + ((seg * 16) ^ ((br & 7) << 4));
  int coff[2];
#pragma unroll
  for (int ks = 0; ks < 2; ++ks)
    coff[ks] = (ks * 64 + quad * 16) ^ (l7 << 4);
  // read row for (ni): wn*32 + ni*16 + l15
  const int rbase = (wn * 32 + l15) * 128;

  f32x4 acc[4][2];
#pragma unroll
  for (int mi = 0; mi < 4; ++mi)
#pragma unroll
    for (int ni = 0; ni < 2; ++ni)
      acc[mi][ni] = (f32x4)(0.f);

  f32x4 rb[2][2];   // 2-slot register prefetch (tile T -> slot T&1), 8 fl each

  // volatile asm loads; "=&v" early-clobber (R5 lesson).
#define BLOAD(T, SLOT)                                                        \
  {                                                                           \
    const float* a_ = bsrc0 + (size_t)(T) * NLEAF;                            \
    asm volatile(                                                             \
        "global_load_dwordx4 %0, %2, off\n\t"                                 \
        "global_load_dwordx4 %1, %2, off offset:16"                           \
        : "=&v"(rb[SLOT][0]), "=&v"(rb[SLOT][1])                              \
        : "v"(a_) : "memory");                                                \
  }

  // counted wait tied to the slot's regs (SSA deps keep consumers below).
#define BWAIT_(SLOT, N)                                                       \
  asm volatile("s_waitcnt vmcnt(" #N ")"                                      \
               : "+v"(rb[SLOT][0]), "+v"(rb[SLOT][1])::"memory");
#define BWAIT(SLOT, N) BWAIT_(SLOT, N)

#define BSTAGE(SLOT, BUF, SUB)                                                \
  {                                                                           \
    HF8 c0_;                                                                  \
    f32x4 a0_ = rb[SLOT][0], a1_ = rb[SLOT][1];                               \
    c0_.h2[0] = pkrtz(a0_[0], a0_[1]);                                        \
    c0_.h2[1] = pkrtz(a0_[2], a0_[3]);                                        \
    c0_.h2[2] = pkrtz(a1_[0], a1_[1]);                                        \
    c0_.h2[3] = pkrtz(a1_[2], a1_[3]);                                        \
    *(uint4*)(bs8 + (BUF) * 16384 + (SUB) * 8192 + woff) = c0_.u;             \
  }

  // lgkm-only barrier — global prefetch stays in flight across it.
#define BARRIER() asm volatile("s_waitcnt lgkmcnt(0)\n\ts_barrier" ::: "memory")

#define COMPUTE(IT, BUF, SUB)                                                 \
  {                                                                           \
    float xvf[4];                                                             \
    _Float16 xh[4];                                                           \
    _Pragma("unroll")                                                         \
    for (int mi = 0; mi < 4; ++mi) xvf[mi] = xs[(IT)][wm + mi * 16 + l15];    \
    _Pragma("unroll")                                                         \
    for (int mi = 0; mi < 4; ++mi) xh[mi] = (_Float16)xvf[mi];                \
    const unsigned char* bsr_ = bs8 + (BUF) * 16384 + (SUB) * 8192;           \
    __builtin_amdgcn_s_setprio(1);                                            \
    _Pragma("unroll")                                                         \
    for (int ks = 0; ks < 2; ++ks) {                                          \
      h16x8 af[4];                                                            \
      _Pragma("unroll")                                                       \
      for (int mi = 0; mi < 4; ++mi) {                                        \
        HF8 t_;                                                               \
        f16x2 xp_; xp_[0] = xh[mi]; xp_[1] = xh[mi];                          \
        _Pragma("unroll")                                                     \
        for (int j = 0; j < 4; ++j) t_.h2[j] = prh[mi][ks].h2[j] * xp_;       \
        af[mi] = t_.v;                                                        \
      }                                                                       \
      _Pragma("unroll")                                                       \
      for (int ni = 0; ni < 2; ++ni) {                                        \
        h16x8 bfr = *(const h16x8*)(bsr_ + ni * 2048 + rbase + coff[ks]);     \
        _Pragma("unroll")                                                     \
        for (int mi = 0; mi < 4; ++mi)                                        \
          acc[mi][ni] = __builtin_amdgcn_mfma_f32_16x16x32_f16(               \
              af[mi], bfr, acc[mi][ni], 0, 0, 0);                             \
      }                                                                       \
    }                                                                         \
    __builtin_amdgcn_s_setprio(0);                                            \
  }

// Phase: bs[BUF] holds tiles {IT0, IT0+1}; stages IT0+2,IT0+3 into bs[BUF^1];
// optionally loads IT0+4, IT0+5. Tiles even->slot0, odd->slot1.
#define PHASE(IT0, BUF, WA, WB, DL)                                           \
  {                                                                           \
    COMPUTE(IT0, BUF, 0)                                                      \
    BWAIT(0, WA)                                                              \
    BSTAGE(0, (BUF) ^ 1, 0)                                                   \
    if (DL) { BLOAD((IT0) + 4, 0) }                                           \
    COMPUTE((IT0) + 1, BUF, 1)                                                \
    BWAIT(1, WB)                                                              \
    BSTAGE(1, (BUF) ^ 1, 1)                                                   \
    if (DL) { BLOAD((IT0) + 5, 1) }                                           \
    BARRIER();                                                                \
  }

  // ---- prologue: tiles 0,1 issued; stage 0,1; issue 2,3 ----
  BLOAD(0, 0)
  BLOAD(1, 1)
  BWAIT(0, 2)
  BSTAGE(0, 0, 0)
  BLOAD(2, 0)
  BWAIT(1, 2)
  BSTAGE(1, 0, 1)
  BLOAD(3, 1)
  BARRIER();         // xs + bs[0] visible; tiles {2,3} in flight

  // ---- steady phases p=0..13 (compute tiles 0..27; loads through 31) ----
  for (int it0 = 0; it0 < 28; it0 += 4) {
    PHASE(it0 + 0, 0, 2, 2, 1)
    PHASE(it0 + 2, 1, 2, 2, 1)
  }
  // ---- drain: p14 computes 28,29; stages 30,31; no loads ----
  PHASE(28, 0, 2, 0, 0)
  // ---- final pair (bs buf 1 holds 30,31) ----
  COMPUTE(30, 1, 0)
  COMPUTE(31, 1, 1)

#undef BLOAD
#undef BWAIT
#undef BWAIT_
#undef BSTAGE
#undef BARRIER
#undef COMPUTE
#undef PHASE

  // ---- pb fold: kc==0 blocks add p @ pb^T via one pseudo-i-step ----
  if (kc == 0) {
    {
      const float* pbs = pb + (size_t)(o0 + br) * NLEAF + seg * 8;
      float4 a0_ = *(const float4*)(pbs);
      float4 a1_ = *(const float4*)(pbs + 4);
      HF8 c0_;
      c0_.h2[0] = pkrtz(a0_.x, a0_.y);
      c0_.h2[1] = pkrtz(a0_.z, a0_.w);
      c0_.h2[2] = pkrtz(a1_.x, a1_.y);
      c0_.h2[3] = pkrtz(a1_.z, a1_.w);
      *(uint4*)(bs8 + woff) = c0_.u;   // buf0 sub0 — all reads done (BARRIER)
    }
    __syncthreads();
    const unsigned char* bsr_ = bs8;
#pragma unroll
    for (int ks = 0; ks < 2; ++ks) {
#pragma unroll
      for (int ni = 0; ni < 2; ++ni) {
        h16x8 bfr = *(const h16x8*)(bsr_ + ni * 2048 + rbase + coff[ks]);
#pragma unroll
        for (int mi = 0; mi < 4; ++mi)
          acc[mi][ni] = __builtin_amdgcn_mfma_f32_16x16x32_f16(
              prh[mi][ks].v, bfr, acc[mi][ni], 0, 0, 0);
      }
    }
  }

  // ---- epilogue ----
#pragma unroll
  for (int mi = 0; mi < 4; ++mi) {
#pragma unroll
    for (int ni = 0; ni < 2; ++ni) {
      int row = row_m0 + wm + mi * 16 + quad * 4;
      int col = o0 + wn * 32 + ni * 16 + l15;
      if (ATOMIC) {
        float* o = dst + (size_t)row * OUT_F + col;
        atomicAdd(o,             acc[mi][ni][0]);
        atomicAdd(o + OUT_F,     acc[mi][ni][1]);
        atomicAdd(o + 2 * OUT_F, acc[mi][ni][2]);
        atomicAdd(o + 3 * OUT_F, acc[mi][ni][3]);
      } else {
        float* o = dst + ((size_t)kc << 19) + (size_t)row * OUT_F + col;
        o[0]         = acc[mi][ni][0];
        o[OUT_F]     = acc[mi][ni][1];
        o[2 * OUT_F] = acc[mi][ni][2];
        o[3 * OUT_F] = acc[mi][ni][3];
      }
    }
  }
}

// ---------------------------------------------------------------------------
// Kernel 3 (slim): out = sum_kc parts[kc]  (pb handled in k_fused).
// nparts==0 -> zero-init for the atomic fallback.
// ---------------------------------------------------------------------------
__global__ __launch_bounds__(256, 8) void k_reduce(
    const float* __restrict__ parts, float* __restrict__ out, int nparts)
{
  const int idx = blockIdx.x * 256 + threadIdx.x;   // f32x4 index, 131072 total
  f32x4 a = (f32x4)(0.f);
#pragma unroll 8
  for (int k = 0; k < nparts; ++k)
    a += ((const f32x4*)(parts + ((size_t)k << 19)))[idx];
  ((f32x4*)out)[idx] = a;
}

// ---------------------------------------------------------------------------
extern "C" void kernel_launch(void* const* d_in, const int* in_sizes, int n_in,
                              void* d_out, int out_size, void* d_ws, size_t ws_size,
                              hipStream_t stream) {
  const float* xg = (const float*)d_in[0];   // x_gating [1024][512]
  const float* xl = (const float*)d_in[1];   // x_leaf   [1024][512]
  const float* gw = (const float*)d_in[2];   // [512][63]
  const float* gb = (const float*)d_in[3];   // [63]
  const float* pw = (const float*)d_in[4];   // [512][512][64]
  const float* pb = (const float*)d_in[5];   // [512][64]
  float* out = (float*)d_out;

  // ws: p fp32 (256 KB) | parts fp32 [SK][1024][512] (32 MB)
  const size_t P_BYTES = (size_t)B_SZ * NLEAF * 4;
  const size_t SLICE   = (size_t)B_SZ * OUT_F * 4;

  float* p_ws  = (float*)d_ws;
  float* parts = (float*)((char*)d_ws + P_BYTES);

  k_leafprobs<<<dim3(B_SZ), dim3(512), 0, stream>>>(xg, gw, gb, p_ws);

  if (ws_size >= P_BYTES + SK * SLICE) {
    k_fused<false><<<dim3(512), dim3(512), 0, stream>>>(xl, p_ws, pw, pb, parts);
    k_reduce<<<dim3(512), dim3(256), 0, stream>>>(parts, out, SK);
  } else {
    k_reduce<<<dim3(512), dim3(256), 0, stream>>>(parts, out, 0);
    k_fused<true><<<dim3(512), dim3(512), 0, stream>>>(xl, p_ws, pw, pb, out);
  }
}